// Round 5
// baseline (518.186 us; speedup 1.0000x reference)
//
#include <hip/hip_runtime.h>
#include <math.h>

// OHNM loss: pos BCE sum + top-k(600000) negative softplus sum, mean over 800000.
//
// R12: R11's fused gather-sync, minus the spin-storm. R11 post-mortem: 16
// arrival counters shared ONE cache line, hammered by 4096 tight-loop
// scope-agent acquire-loads while 2048 release-RMWs fought for exclusive
// ownership -> arrivals serialized (~300us) and probe flood throttled the
// whole chip (VALUBusy 3.6%, HBM 135GB/s). Fixes:
//   * counters padded to one per 256B line (16 lines per set)
//   * GO-flag broadcast: only block 0's 16 lanes poll counters; blocks
//     1..511 poll a single write-once GO word; all spins s_sleep(8) backoff
//   * LDS union (slow-path overlays the 16KB hist) -> ~18KB -> 8 blocks/CU
//     -> all 2048 blocks co-resident in phase 1
//   * phase B widened to 512 blocks (REG2=64, lambda~4.3/wave, +14sigma)
// Structure unchanged otherwise:
//   phase 1 (2048x256): stream x,y -> pos partials, per-wave cand compact
//     (ballot cursors), LDS L1 hist -> atomic merge into 16 partials.
//     Arrive on padded ARR1; blocks >= 512 EXIT (leavers never wait).
//   phase B (0..511): block 0 polls ARR1 then release-stores GO; others poll
//     GO. Redundant slot-reduce -> hard; scan1 -> b1; ONE cand stream:
//     sure-sum + b1-key compaction into per-wave regions. Arrive ARR2;
//     blocks 1..511 exit.
//   phase C (block 0): poll ARR2; hist2(4096 LDS) from ~9K region keys,
//     scan2, s2+hist3(16), scan3, combine -> out.
// Anomalies (count shortfall / x>=256 / region overflow) -> correct
// single-block slow fallback (never taken for this input).

#define K0 0xBF800000u             // f2key(1.0f)
#define FINE_LIMIT 0xC3800000u     // f2key(256.0f)
#define GRID 2048
#define NT 256                     // threads per block
#define NWAVES 8192                // GRID x 4 waves
#define REG 256                    // cand words per wave (lambda=159, +7.9 sigma)
#define NPART 16                   // L1 partial hists (atomic-merged, pre-zeroed)
#define BBLK 512                   // surviving blocks for phase B
#define SELWAVES (BBLK * (NT/64))  // 2048 phase-B waves
#define REG2 64                    // b1-key region words per phase-B wave (mean ~4.3)
#define NCTR 16                    // split arrival counters
#define CSTRIDE 64                 // words between counters (256B, own line)

// ---- ws layout (word offsets) ----
#define OFF_FLG  8                               // pre-zeroed
#define OFF_GO1  12                              // pre-zeroed
#define OFF_ARR1 64                              // 16 counters, stride 64 w
#define OFF_ARR2 (OFF_ARR1 + NCTR * CSTRIDE)     // 1088
#define OFF_H1P  (OFF_ARR2 + NCTR * CSTRIDE)     // 2112: 16x1024 partials
#define OFF_CNT  (OFF_H1P + NPART * 1024)        // 18496: per-wave counts
#define OFF_POSP (OFF_CNT + NWAVES)              // 26688: per-wave pos (f32)
#define OFF_MAXK (OFF_POSP + NWAVES)             // 34880: per-wave maxkey
#define OFF_SS   (OFF_MAXK + NWAVES)             // 43072: 512 sure-sums (f32)
#define OFF_CNT2 (OFF_SS + BBLK)                 // 43584: 2048 region counts
#define OFF_CAND2 (OFF_CNT2 + SELWAVES)          // 45632: 2048 x 64 regions
#define OFF_CAND (OFF_CAND2 + SELWAVES * REG2)   // 176704 (16B aligned)
#define CANDW    (NWAVES * REG)                  // 2,097,152 words (8 MB)
#define ZERO_BYTES (OFF_CNT * 4)                 // 73984 B

__device__ __forceinline__ unsigned f2key(float x) {
    unsigned u = __float_as_uint(x);
    return (u & 0x80000000u) ? ~u : (u | 0x80000000u);
}
__device__ __forceinline__ float key2f(unsigned k) {
    unsigned u = (k & 0x80000000u) ? (k & 0x7FFFFFFFu) : ~k;
    return __uint_as_float(u);
}
__device__ __forceinline__ float softplusf(float x) {
    return fmaxf(x, 0.0f) + __logf(1.0f + __expf(-fabsf(x)));
}
__device__ __forceinline__ float wred(float v) {
    v += __shfl_down(v, 32); v += __shfl_down(v, 16); v += __shfl_down(v, 8);
    v += __shfl_down(v, 4);  v += __shfl_down(v, 2);  v += __shfl_down(v, 1);
    return v;
}
__device__ __forceinline__ unsigned wredmax(unsigned v) {
    v = max(v, (unsigned)__shfl_down((int)v, 32));
    v = max(v, (unsigned)__shfl_down((int)v, 16));
    v = max(v, (unsigned)__shfl_down((int)v, 8));
    v = max(v, (unsigned)__shfl_down((int)v, 4));
    v = max(v, (unsigned)__shfl_down((int)v, 2));
    v = max(v, (unsigned)__shfl_down((int)v, 1));
    return v;
}
// block float-sum; result valid on thread 0
__device__ float bred(float v) {
    __shared__ float sb[16];
    const int lane = threadIdx.x & 63, w = threadIdx.x >> 6;
    const int nw = blockDim.x >> 6;
    v = wred(v);
    if (lane == 0) sb[w] = v;
    __syncthreads();
    float r = 0.0f;
    if (threadIdx.x == 0) for (int i = 0; i < nw; ++i) r += sb[i];
    __syncthreads();
    return r;
}
// block reduce of (sum tot, max mk, or ov, fsum ps); results broadcast to all
__device__ void blockreduce4(unsigned& tot, unsigned& mk, unsigned& ov, float& ps) {
    __shared__ unsigned st[4], sm_[4], so[4];
    __shared__ float sf[4];
    __shared__ unsigned rbu[3];
    __shared__ float rbf;
    const int lane = threadIdx.x & 63, w = threadIdx.x >> 6;
    const int nw = blockDim.x >> 6;
    tot += __shfl_down(tot, 32); tot += __shfl_down(tot, 16); tot += __shfl_down(tot, 8);
    tot += __shfl_down(tot, 4);  tot += __shfl_down(tot, 2);  tot += __shfl_down(tot, 1);
    mk = wredmax(mk);
    ov |= (unsigned)__shfl_down((int)ov, 32); ov |= (unsigned)__shfl_down((int)ov, 16);
    ov |= (unsigned)__shfl_down((int)ov, 8);  ov |= (unsigned)__shfl_down((int)ov, 4);
    ov |= (unsigned)__shfl_down((int)ov, 2);  ov |= (unsigned)__shfl_down((int)ov, 1);
    ps = wred(ps);
    if (lane == 0) { st[w] = tot; sm_[w] = mk; so[w] = ov; sf[w] = ps; }
    __syncthreads();
    if (threadIdx.x == 0) {
        unsigned T = 0, M = 0, O = 0; float P = 0.0f;
        for (int i = 0; i < nw; ++i) { T += st[i]; M = max(M, sm_[i]); O |= so[i]; P += sf[i]; }
        rbu[0] = T; rbu[1] = M; rbu[2] = O; rbf = P;
    }
    __syncthreads();
    tot = rbu[0]; mk = rbu[1]; ov = rbu[2]; ps = rbf;
    __syncthreads();
}

// descending rank-select, summing nparts partial hists; redundant per block.
template<int NTH>
__device__ void scan_desc(const unsigned* __restrict__ hist, int nparts,
                          int pstride, int nbins, unsigned R,
                          unsigned* bin_out, unsigned* r_out) {
    __shared__ unsigned sums[NTH];
    __shared__ unsigned res[2];
    const int per = nbins / NTH;
    const int t = threadIdx.x;
    unsigned local[16];
    unsigned s = 0;
    for (int j = 0; j < per; ++j) {
        const int bin = nbins - 1 - (t * per + j);
        unsigned v = 0;
        for (int p = 0; p < nparts; ++p) v += hist[p * pstride + bin];
        local[j] = v;
        s += v;
    }
    if (t == 0) { res[0] = 0u; res[1] = 1u; }
    sums[t] = s;
    __syncthreads();
    for (int off = 1; off < NTH; off <<= 1) {
        unsigned v = (t >= off) ? sums[t - off] : 0u;
        __syncthreads();
        sums[t] += v;
        __syncthreads();
    }
    const unsigned incl = sums[t], excl = incl - s;
    if (excl < R && incl >= R) {
        unsigned cum = excl;
        for (int j = 0; j < per; ++j) {
            if (cum + local[j] >= R) {
                res[0] = (unsigned)(nbins - 1 - (t * per + j));
                res[1] = R - cum;
                break;
            }
            cum += local[j];
        }
    }
    __syncthreads();
    *bin_out = res[0];
    *r_out = res[1];
    __syncthreads();
}

// fine bins: kp = k - K0 (only for k in [K0, FINE_LIMIT))
__device__ __forceinline__ unsigned fl1(unsigned kp) { return kp >> 16; }
__device__ __forceinline__ unsigned fl2(unsigned kp) { return (kp >> 4) & 0xFFFu; }
__device__ __forceinline__ unsigned fl3(unsigned kp) { return kp & 0xFu; }
// hard (coarse) bins: full key range
__device__ __forceinline__ unsigned hl1(unsigned k) { return k >> 22; }
__device__ __forceinline__ unsigned hl2(unsigned k) { return (k >> 10) & 0xFFFu; }
__device__ __forceinline__ unsigned hl3(unsigned k) { return k & 0x3FFu; }

// ---- correct single-block fallback: coarse 3-level select from x,y ----
// Never taken for the bench input. Block 0, NT threads. ha = 4096-word LDS,
// reused across phases (h3c/h3f overlay ha[0..2047] after b2 is fixed).
__device__ void slow_select(const float* __restrict__ x, const float* __restrict__ y,
                            unsigned* __restrict__ ws, int n, unsigned Kneg, int pos,
                            float psum, float* __restrict__ out, unsigned* ha) {
    const int t = threadIdx.x;
    __shared__ unsigned bc[2];
    // L1 coarse
    for (int i = t; i < 1024; i += NT) ha[i] = 0u;
    __syncthreads();
    for (int i = t; i < n; i += NT)
        if (y[i] == 0.0f) atomicAdd(&ha[hl1(f2key(x[i]))], 1u);
    __syncthreads();
    if (t == 0) {
        unsigned cum = 0, b = 0, r = 1;
        for (int bin = 1023; bin >= 0; --bin) {
            unsigned v = ha[bin];
            if (cum + v >= Kneg) { b = (unsigned)bin; r = Kneg - cum; break; }
            cum += v;
        }
        bc[0] = b; bc[1] = r;
    }
    __syncthreads();
    const unsigned b1 = bc[0], r1 = bc[1];
    __syncthreads();
    // L2
    for (int i = t; i < 4096; i += NT) ha[i] = 0u;
    __syncthreads();
    float ss = 0.0f;
    for (int i = t; i < n; i += NT)
        if (y[i] == 0.0f) {
            unsigned k = f2key(x[i]);
            unsigned b = hl1(k);
            if (b > b1) ss += softplusf(key2f(k));
            else if (b == b1) atomicAdd(&ha[hl2(k)], 1u);
        }
    __syncthreads();
    if (t == 0) {
        unsigned cum = 0, b = 0, r = 1;
        for (int bin = 4095; bin >= 0; --bin) {
            unsigned v = ha[bin];
            if (cum + v >= r1) { b = (unsigned)bin; r = r1 - cum; break; }
            cum += v;
        }
        bc[0] = b; bc[1] = r;
    }
    __syncthreads();
    const unsigned b2 = bc[0], r2 = bc[1];
    __syncthreads();
    // L3 (overlay ha[0..2047]; hist data no longer needed)
    unsigned* h3c = ha;
    float* h3f = (float*)(ha + 1024);
    for (int i = t; i < 2048; i += NT) ha[i] = 0u;
    __syncthreads();
    float s2 = 0.0f;
    for (int i = t; i < n; i += NT)
        if (y[i] == 0.0f) {
            unsigned k = f2key(x[i]);
            if (hl1(k) == b1) {
                unsigned l2 = hl2(k);
                if (l2 > b2) s2 += softplusf(key2f(k));
                else if (l2 == b2) {
                    atomicAdd(&h3c[hl3(k)], 1u);
                    atomicAdd(&h3f[hl3(k)], softplusf(key2f(k)));
                }
            }
        }
    __syncthreads();
    ss = bred(ss);
    s2 = bred(s2);
    if (t == 0) {
        unsigned cum = 0, c3 = 0, r3 = 1;
        for (int bin = 1023; bin >= 0; --bin) {
            unsigned v = h3c[bin];
            if (cum + v >= r2) { c3 = (unsigned)bin; r3 = r2 - cum; break; }
            cum += v;
        }
        float sf = 0.0f;
        for (int j = (int)c3 + 1; j < 1024; ++j) sf += h3f[j];
        unsigned H = (b1 << 22) | (b2 << 10) | c3;
        out[0] = (psum + ss + s2 + sf + (float)r3 * softplusf(key2f(H)))
                 / (float)(4 * pos);
    }
}

// ---- k_fused: phases 1 / B / C with padded gather sync + GO broadcast ----
__global__ __launch_bounds__(NT)
void k_fused(const float* __restrict__ x, const float* __restrict__ y,
             unsigned* __restrict__ ws, const int* __restrict__ pos_num,
             unsigned cap_words, int n, float* __restrict__ out) {
    __shared__ unsigned smbuf[4096];   // ph1: L1 hist(1024); C: hist2; slow: ha
    __shared__ unsigned h3c[16];
    __shared__ float    h3f[16];
    const int tid = threadIdx.x;
    const int lane = tid & 63;

    // ======== Phase 1: stream x,y ========
    const unsigned waveid = blockIdx.x * 4 + (tid >> 6);
    unsigned* cand = ws + OFF_CAND;
    const unsigned base = waveid * REG;
    for (int i = tid; i < 1024; i += NT) smbuf[i] = 0u;
    __syncthreads();

    float ps = 0.0f;
    unsigned kmax = 0u, cur = 0u, ovf = 0u;
    const int n4 = n >> 2;
    const float4* x4 = (const float4*)x;
    const float4* y4 = (const float4*)y;
    const unsigned gtid = blockIdx.x * NT + tid;
    const unsigned gstride = GRID * NT;
    for (unsigned i = gtid; i < (unsigned)n4; i += gstride) {
        float4 xv = x4[i];
        float4 yv = y4[i];
        float xs[4] = {xv.x, xv.y, xv.z, xv.w};
        float ys[4] = {yv.x, yv.y, yv.z, yv.w};
#pragma unroll
        for (int c = 0; c < 4; ++c) {
            bool pos = ys[c] > 0.0f;
            if (pos) ps += softplusf(-xs[c]);
            unsigned k = f2key(xs[c]);
            bool cnd = (!pos) && (k >= K0);
            unsigned long long mask = __ballot(cnd);
            if (mask) {
                if (cnd) {
                    kmax = max(kmax, k);
                    unsigned b = fl1(k - K0); if (b > 1023u) b = 1023u;
                    atomicAdd(&smbuf[b], 1u);
                    unsigned slot = cur + (unsigned)__popcll(mask & ((1ull << lane) - 1ull));
                    unsigned gi = base + slot;
                    if (slot < REG && gi < cap_words) cand[gi] = k;
                    else ovf = 1u;
                }
                cur += (unsigned)__popcll(mask);
            }
        }
    }
    // tail (n % 4): wave 0, all lanes (keeps cur uniform)
    if (waveid == 0) {
        for (int i = (n & ~3) + lane; i < n; i += 64) {
            float xs = x[i];
            bool pos = y[i] > 0.0f;
            if (pos) ps += softplusf(-xs);
            unsigned k = f2key(xs);
            bool cnd = (!pos) && (k >= K0);
            unsigned long long mask = __ballot(cnd);
            if (mask) {
                if (cnd) {
                    kmax = max(kmax, k);
                    unsigned b = fl1(k - K0); if (b > 1023u) b = 1023u;
                    atomicAdd(&smbuf[b], 1u);
                    unsigned slot = cur + (unsigned)__popcll(mask & ((1ull << lane) - 1ull));
                    unsigned gi = base + slot;
                    if (slot < REG && gi < cap_words) cand[gi] = k;
                    else ovf = 1u;
                }
                cur += (unsigned)__popcll(mask);
            }
        }
    }
    // zero-fill padding (later phases skip k < K0; 0 < K0)
    for (unsigned j = cur + lane; j < REG; j += 64) {
        unsigned gi = base + j;
        if (gi < cap_words) cand[gi] = 0u;
    }
    if (base + REG > cap_words) ovf = 1u;
    ps = wred(ps);
    kmax = wredmax(kmax);
    unsigned anyovf = (__ballot(ovf != 0u) != 0ull) ? 0x80000000u : 0u;
    if (lane == 0) {
        ws[OFF_CNT + waveid] = (cur & 0x7FFFFFFFu) | anyovf;
        ((float*)ws)[OFF_POSP + waveid] = ps;
        ws[OFF_MAXK + waveid] = kmax;
    }
    __syncthreads();
    // merge LDS hist into partial (blockIdx % NPART); only nonzero bins
    {
        unsigned* part = ws + OFF_H1P + (blockIdx.x & (NPART - 1)) * 1024;
        for (int i = tid; i < 1024; i += NT)
            if (smbuf[i]) atomicAdd(&part[i], smbuf[i]);
    }

    // ---- arrive #1 (release, padded counters); blocks >= BBLK exit ----
    __syncthreads();
    __threadfence();
    if (tid == 0)
        __hip_atomic_fetch_add(&ws[OFF_ARR1 + (blockIdx.x & (NCTR - 1)) * CSTRIDE],
                               1u, __ATOMIC_RELEASE, __HIP_MEMORY_SCOPE_AGENT);
    if (blockIdx.x >= BBLK) return;

    // ---- block 0 polls counters then broadcasts GO; others poll GO ----
    if (blockIdx.x == 0) {
        if (tid < NCTR) {
            while (__hip_atomic_load(&ws[OFF_ARR1 + tid * CSTRIDE], __ATOMIC_ACQUIRE,
                                     __HIP_MEMORY_SCOPE_AGENT) < (GRID / NCTR))
                __builtin_amdgcn_s_sleep(8);
        }
        __syncthreads();
        __threadfence();
        if (tid == 0)
            __hip_atomic_store(&ws[OFF_GO1], 1u, __ATOMIC_RELEASE,
                               __HIP_MEMORY_SCOPE_AGENT);
    } else {
        if (tid == 0) {
            while (__hip_atomic_load(&ws[OFF_GO1], __ATOMIC_ACQUIRE,
                                     __HIP_MEMORY_SCOPE_AGENT) == 0u)
                __builtin_amdgcn_s_sleep(8);
        }
        __syncthreads();
        __threadfence();
    }

    // ======== Phase B (blocks 0..511) ========
    const int posn = pos_num[0];
    const unsigned Kneg = (unsigned)(posn * 3);
    unsigned tot = 0u, mk = 0u, ov = 0u;
    float psum = 0.0f;
    for (unsigned i = tid; i < NWAVES; i += NT) {
        unsigned cc = ws[OFF_CNT + i];
        tot += cc & 0x7FFFFFFFu;
        ov |= cc >> 31;
        mk = max(mk, ws[OFF_MAXK + i]);
        psum += ((float*)ws)[OFF_POSP + i];
    }
    blockreduce4(tot, mk, ov, psum);
    const bool hard = (tot < Kneg) || (mk >= FINE_LIMIT) || (ov != 0u);

    unsigned b1 = 0u, r1 = 1u;
    if (!hard) {
        scan_desc<NT>(ws + OFF_H1P, NPART, 1024, 1024, Kneg, &b1, &r1);
        const unsigned wv = blockIdx.x * (NT / 64) + (unsigned)(tid >> 6);
        unsigned cur2 = 0u;
        float ssv = 0.0f;
        const uint4* c4 = (const uint4*)(ws + OFF_CAND);
        for (unsigned i = blockIdx.x * NT + tid; i < (unsigned)(CANDW / 4); i += BBLK * NT) {
            uint4 v = c4[i];
            unsigned ks[4] = {v.x, v.y, v.z, v.w};
#pragma unroll
            for (int cc = 0; cc < 4; ++cc) {
                unsigned k = ks[cc];
                bool ge = (k >= K0);
                unsigned b = ge ? fl1(k - K0) : 0u;
                if (ge && b > b1) ssv += softplusf(key2f(k));
                bool hit = ge && (b == b1);
                unsigned long long m = __ballot(hit);
                if (m) {
                    if (hit) {
                        unsigned slot = cur2 + (unsigned)__popcll(m & ((1ull << lane) - 1ull));
                        if (slot < (unsigned)REG2) ws[OFF_CAND2 + wv * REG2 + slot] = k;
                    }
                    cur2 += (unsigned)__popcll(m);
                }
            }
        }
        if (lane == 0) {
            ws[OFF_CNT2 + wv] = cur2 < (unsigned)REG2 ? cur2 : (unsigned)REG2;
            if (cur2 > (unsigned)REG2) ws[OFF_FLG] = 1u;   // benign same-value race
        }
        ssv = bred(ssv);
        if (tid == 0) ((float*)ws)[OFF_SS + blockIdx.x] = ssv;
    }

    // ---- arrive #2 (release, padded); blocks 1..511 exit ----
    __syncthreads();
    __threadfence();
    if (tid == 0)
        __hip_atomic_fetch_add(&ws[OFF_ARR2 + (blockIdx.x & (NCTR - 1)) * CSTRIDE],
                               1u, __ATOMIC_RELEASE, __HIP_MEMORY_SCOPE_AGENT);
    if (blockIdx.x != 0) return;

    if (tid < NCTR) {
        while (__hip_atomic_load(&ws[OFF_ARR2 + tid * CSTRIDE], __ATOMIC_ACQUIRE,
                                 __HIP_MEMORY_SCOPE_AGENT) < (BBLK / NCTR))
            __builtin_amdgcn_s_sleep(8);
    }
    __syncthreads();
    __threadfence();

    // ======== Phase C (block 0) ========
    const bool slow = hard || (ws[OFF_FLG] != 0u);
    if (slow) {
        slow_select(x, y, ws, n, Kneg, posn, psum, out, smbuf);
        return;
    }
    // hist2 over b1-keys from per-wave global regions
    for (int i = tid; i < 4096; i += NT) smbuf[i] = 0u;
    __syncthreads();
    for (int rr = 0; rr < SELWAVES / NT; ++rr) {
        const unsigned region = (unsigned)tid + (unsigned)rr * NT;
        const unsigned cnt = ws[OFF_CNT2 + region];      // clamped <= REG2
        const unsigned rbase = OFF_CAND2 + region * REG2;
        for (unsigned j = 0; j < cnt; ++j)
            atomicAdd(&smbuf[fl2(ws[rbase + j] - K0)], 1u);
    }
    __syncthreads();
    unsigned b2, r2;
    scan_desc<NT>(smbuf, 1, 0, 4096, r1, &b2, &r2);
    if (tid < 16) { h3c[tid] = 0u; h3f[tid] = 0.0f; }
    __syncthreads();
    float s2 = 0.0f;
    for (int rr = 0; rr < SELWAVES / NT; ++rr) {
        const unsigned region = (unsigned)tid + (unsigned)rr * NT;
        const unsigned cnt = ws[OFF_CNT2 + region];
        const unsigned rbase = OFF_CAND2 + region * REG2;
        for (unsigned j = 0; j < cnt; ++j) {
            unsigned k = ws[rbase + j];
            unsigned l2 = fl2(k - K0);
            if (l2 > b2) s2 += softplusf(key2f(k));
            else if (l2 == b2) {
                atomicAdd(&h3c[fl3(k - K0)], 1u);
                atomicAdd(&h3f[fl3(k - K0)], softplusf(key2f(k)));
            }
        }
    }
    __syncthreads();
    s2 = bred(s2);
    float ssv2 = ((float*)ws)[OFF_SS + tid] + ((float*)ws)[OFF_SS + NT + tid];
    float ssT = bred(ssv2);
    if (tid == 0) {
        unsigned cum = 0, c3 = 0, r3 = 1;
        for (int bin = 15; bin >= 0; --bin) {
            unsigned v = h3c[bin];
            if (cum + v >= r2) { c3 = (unsigned)bin; r3 = r2 - cum; break; }
            cum += v;
        }
        float sf = 0.0f;
        for (int j = (int)c3 + 1; j < 16; ++j) sf += h3f[j];
        unsigned H = K0 + ((b1 << 16) | (b2 << 4) | c3);
        out[0] = (psum + ssT + s2 + sf + (float)r3 * softplusf(key2f(H)))
                 / (float)(4 * posn);
    }
}

extern "C" void kernel_launch(void* const* d_in, const int* in_sizes, int n_in,
                              void* d_out, int out_size, void* d_ws, size_t ws_size,
                              hipStream_t stream) {
    const float* x = (const float*)d_in[0];
    const float* y = (const float*)d_in[1];
    const int* pos_num = (const int*)d_in[2];
    float* out = (float*)d_out;
    const int n = in_sizes[0];

    unsigned* ws = (unsigned*)d_ws;
    unsigned cap_words = 0u;
    if (ws_size / 4 > (size_t)OFF_CAND)
        cap_words = (unsigned)(ws_size / 4 - OFF_CAND);
    if (cap_words > (unsigned)CANDW) cap_words = (unsigned)CANDW;

    hipMemsetAsync(d_ws, 0, ZERO_BYTES, stream);   // ctrl + counters + partials
    k_fused<<<GRID, NT, 0, stream>>>(x, y, ws, pos_num, cap_words, n, out);
}

// Round 6
// 164.495 us; speedup vs baseline: 3.1502x; 3.1502x over previous
//
#include <hip/hip_runtime.h>
#include <math.h>

// OHNM loss: pos BCE sum + top-k(600000) negative softplus sum, mean over 800000.
//
// R13: back to the R10 multi-kernel structure (best measured: 139.6us).
// R11/R12 post-mortem: intra-kernel gather sync is structurally bad here --
// waiting blocks HOLD residency slots, so the 2048 arrivals trickle through
// in serialized generations (Occupancy ~35%, kernel 370-460us). Coop launch
// (R9) cost +80us. Lesson: phase boundaries belong at kernel boundaries,
// EXCEPT where no one waits.
// R13 change vs R10: merge k_B+k_C via the TAIL-BLOCK pattern (no waiting):
// each k_BC block ends with one fetch_add on a done-counter and exits; the
// block that draws rank BBLK-1 runs phase C inline (it provably starts after
// all other blocks' stores; acq_rel RMW + threadfence give cross-XCD
// visibility). Deletes one launch boundary + k_C's startup.
//   memset(64KB):  zero FLG/DONE + 16x1024 L1 partials (ws is poisoned)
//   k_main (2048x256): pos_sum + per-wave cand compact (ballot cursors,
//                      0 contended atomics) + LDS L1 hist -> atomic merge
//                      into 16 partials (~200K scattered atomics)
//   k_BC   (256x256):  slot-reduce (hard flag, psum; redundant per block),
//                      scan1 -> b1; ONE cand stream: sure-sum + b1-key
//                      compaction into per-wave regions; tail block:
//                      hist2(4096 LDS) from ~9K region keys, scan2,
//                      s2+hist3(16), scan3, combine -> out
// Anomalies (count shortfall / x>=256 / region overflow) -> correct
// single-block slow fallback in the tail block (never taken here).

#define K0 0xBF800000u             // f2key(1.0f)
#define FINE_LIMIT 0xC3800000u     // f2key(256.0f)
#define GRID 2048
#define NT 256                     // threads per block (both kernels)
#define NWAVES 8192                // GRID x 4 waves
#define REG 256                    // cand words per wave (lambda=159, +7.9 sigma)
#define NPART 16                   // L1 partial hists (atomic-merged, pre-zeroed)
#define BBLK 256                   // k_BC blocks
#define SELWAVES (BBLK * (NT/64))  // 1024 k_BC waves
#define REG2 128                   // b1-key region words per k_BC wave (mean ~8.7)

// ---- ws layout (word offsets) ----
#define OFF_FLG  8                               // pre-zeroed
#define OFF_DONE 12                              // pre-zeroed tail counter
#define OFF_H1P  64                              // 16 x 1024 L1 partials (pre-zeroed)
#define OFF_CNT  (OFF_H1P + NPART * 1024)        // 16448: per-wave counts
#define OFF_POSP (OFF_CNT + NWAVES)              // 24640: per-wave pos partial (f32)
#define OFF_MAXK (OFF_POSP + NWAVES)             // 32832: per-wave maxkey
#define OFF_SS   (OFF_MAXK + NWAVES)             // 41024: 256 sure-sums (f32)
#define OFF_CNT2 (OFF_SS + BBLK)                 // 41280: 1024 region counts
#define OFF_CAND2 (OFF_CNT2 + SELWAVES)          // 42304: 1024 x 128 regions
#define OFF_CAND (OFF_CAND2 + SELWAVES * REG2)   // 173376 (16B aligned)
#define CANDW    (NWAVES * REG)                  // 2,097,152 words (8 MB)
#define ZERO_BYTES (OFF_CNT * 4)                 // 65792 B

__device__ __forceinline__ unsigned f2key(float x) {
    unsigned u = __float_as_uint(x);
    return (u & 0x80000000u) ? ~u : (u | 0x80000000u);
}
__device__ __forceinline__ float key2f(unsigned k) {
    unsigned u = (k & 0x80000000u) ? (k & 0x7FFFFFFFu) : ~k;
    return __uint_as_float(u);
}
__device__ __forceinline__ float softplusf(float x) {
    return fmaxf(x, 0.0f) + __logf(1.0f + __expf(-fabsf(x)));
}
__device__ __forceinline__ float wred(float v) {
    v += __shfl_down(v, 32); v += __shfl_down(v, 16); v += __shfl_down(v, 8);
    v += __shfl_down(v, 4);  v += __shfl_down(v, 2);  v += __shfl_down(v, 1);
    return v;
}
__device__ __forceinline__ unsigned wredmax(unsigned v) {
    v = max(v, (unsigned)__shfl_down((int)v, 32));
    v = max(v, (unsigned)__shfl_down((int)v, 16));
    v = max(v, (unsigned)__shfl_down((int)v, 8));
    v = max(v, (unsigned)__shfl_down((int)v, 4));
    v = max(v, (unsigned)__shfl_down((int)v, 2));
    v = max(v, (unsigned)__shfl_down((int)v, 1));
    return v;
}
// block float-sum; result valid on thread 0
__device__ float bred(float v) {
    __shared__ float sb[16];
    const int lane = threadIdx.x & 63, w = threadIdx.x >> 6;
    const int nw = blockDim.x >> 6;
    v = wred(v);
    if (lane == 0) sb[w] = v;
    __syncthreads();
    float r = 0.0f;
    if (threadIdx.x == 0) for (int i = 0; i < nw; ++i) r += sb[i];
    __syncthreads();
    return r;
}
// block reduce of (sum tot, max mk, or ov, fsum ps); results broadcast to all
__device__ void blockreduce4(unsigned& tot, unsigned& mk, unsigned& ov, float& ps) {
    __shared__ unsigned st[4], sm_[4], so[4];
    __shared__ float sf[4];
    __shared__ unsigned rbu[3];
    __shared__ float rbf;
    const int lane = threadIdx.x & 63, w = threadIdx.x >> 6;
    const int nw = blockDim.x >> 6;
    tot += __shfl_down(tot, 32); tot += __shfl_down(tot, 16); tot += __shfl_down(tot, 8);
    tot += __shfl_down(tot, 4);  tot += __shfl_down(tot, 2);  tot += __shfl_down(tot, 1);
    mk = wredmax(mk);
    ov |= (unsigned)__shfl_down((int)ov, 32); ov |= (unsigned)__shfl_down((int)ov, 16);
    ov |= (unsigned)__shfl_down((int)ov, 8);  ov |= (unsigned)__shfl_down((int)ov, 4);
    ov |= (unsigned)__shfl_down((int)ov, 2);  ov |= (unsigned)__shfl_down((int)ov, 1);
    ps = wred(ps);
    if (lane == 0) { st[w] = tot; sm_[w] = mk; so[w] = ov; sf[w] = ps; }
    __syncthreads();
    if (threadIdx.x == 0) {
        unsigned T = 0, M = 0, O = 0; float P = 0.0f;
        for (int i = 0; i < nw; ++i) { T += st[i]; M = max(M, sm_[i]); O |= so[i]; P += sf[i]; }
        rbu[0] = T; rbu[1] = M; rbu[2] = O; rbf = P;
    }
    __syncthreads();
    tot = rbu[0]; mk = rbu[1]; ov = rbu[2]; ps = rbf;
    __syncthreads();
}

// descending rank-select, summing nparts partial hists; redundant per block.
// All NTH threads call. First bin (from top) with cum >= R; r = R - above (>=1).
template<int NTH>
__device__ void scan_desc(const unsigned* __restrict__ hist, int nparts,
                          int pstride, int nbins, unsigned R,
                          unsigned* bin_out, unsigned* r_out) {
    __shared__ unsigned sums[NTH];
    __shared__ unsigned res[2];
    const int per = nbins / NTH;
    const int t = threadIdx.x;
    unsigned local[16];
    unsigned s = 0;
    for (int j = 0; j < per; ++j) {
        const int bin = nbins - 1 - (t * per + j);
        unsigned v = 0;
        for (int p = 0; p < nparts; ++p) v += hist[p * pstride + bin];
        local[j] = v;
        s += v;
    }
    if (t == 0) { res[0] = 0u; res[1] = 1u; }
    sums[t] = s;
    __syncthreads();
    for (int off = 1; off < NTH; off <<= 1) {
        unsigned v = (t >= off) ? sums[t - off] : 0u;
        __syncthreads();
        sums[t] += v;
        __syncthreads();
    }
    const unsigned incl = sums[t], excl = incl - s;
    if (excl < R && incl >= R) {
        unsigned cum = excl;
        for (int j = 0; j < per; ++j) {
            if (cum + local[j] >= R) {
                res[0] = (unsigned)(nbins - 1 - (t * per + j));
                res[1] = R - cum;
                break;
            }
            cum += local[j];
        }
    }
    __syncthreads();
    *bin_out = res[0];
    *r_out = res[1];
    __syncthreads();
}

// fine bins: kp = k - K0 (only for k in [K0, FINE_LIMIT))
__device__ __forceinline__ unsigned fl1(unsigned kp) { return kp >> 16; }
__device__ __forceinline__ unsigned fl2(unsigned kp) { return (kp >> 4) & 0xFFFu; }
__device__ __forceinline__ unsigned fl3(unsigned kp) { return kp & 0xFu; }
// hard (coarse) bins: full key range
__device__ __forceinline__ unsigned hl1(unsigned k) { return k >> 22; }
__device__ __forceinline__ unsigned hl2(unsigned k) { return (k >> 10) & 0xFFFu; }
__device__ __forceinline__ unsigned hl3(unsigned k) { return k & 0x3FFu; }

// ---- k_main: pos_sum + per-wave compact + LDS L1 hist -> partial merge ----
__global__ __launch_bounds__(NT)
void k_main(const float* __restrict__ x, const float* __restrict__ y,
            unsigned* __restrict__ ws, unsigned cap_words, int n) {
    __shared__ unsigned h[1024];
    const int tid = threadIdx.x;
    const int lane = tid & 63;
    const unsigned waveid = blockIdx.x * 4 + (tid >> 6);
    unsigned* cand = ws + OFF_CAND;
    const unsigned base = waveid * REG;
    for (int i = tid; i < 1024; i += NT) h[i] = 0u;
    __syncthreads();

    float ps = 0.0f;
    unsigned kmax = 0u, cur = 0u, ovf = 0u;
    const int n4 = n >> 2;
    const float4* x4 = (const float4*)x;
    const float4* y4 = (const float4*)y;
    const unsigned gtid = blockIdx.x * NT + tid;
    const unsigned gstride = GRID * NT;
    for (unsigned i = gtid; i < (unsigned)n4; i += gstride) {
        float4 xv = x4[i];
        float4 yv = y4[i];
        float xs[4] = {xv.x, xv.y, xv.z, xv.w};
        float ys[4] = {yv.x, yv.y, yv.z, yv.w};
#pragma unroll
        for (int c = 0; c < 4; ++c) {
            bool pos = ys[c] > 0.0f;
            if (pos) ps += softplusf(-xs[c]);
            unsigned k = f2key(xs[c]);
            bool cnd = (!pos) && (k >= K0);
            unsigned long long mask = __ballot(cnd);
            if (mask) {
                if (cnd) {
                    kmax = max(kmax, k);
                    unsigned b = fl1(k - K0); if (b > 1023u) b = 1023u;
                    atomicAdd(&h[b], 1u);
                    unsigned slot = cur + (unsigned)__popcll(mask & ((1ull << lane) - 1ull));
                    unsigned gi = base + slot;
                    if (slot < REG && gi < cap_words) cand[gi] = k;
                    else ovf = 1u;
                }
                cur += (unsigned)__popcll(mask);
            }
        }
    }
    // tail (n % 4): wave 0, all lanes (keeps cur uniform)
    if (waveid == 0) {
        for (int i = (n & ~3) + lane; i < n; i += 64) {
            float xs = x[i];
            bool pos = y[i] > 0.0f;
            if (pos) ps += softplusf(-xs);
            unsigned k = f2key(xs);
            bool cnd = (!pos) && (k >= K0);
            unsigned long long mask = __ballot(cnd);
            if (mask) {
                if (cnd) {
                    kmax = max(kmax, k);
                    unsigned b = fl1(k - K0); if (b > 1023u) b = 1023u;
                    atomicAdd(&h[b], 1u);
                    unsigned slot = cur + (unsigned)__popcll(mask & ((1ull << lane) - 1ull));
                    unsigned gi = base + slot;
                    if (slot < REG && gi < cap_words) cand[gi] = k;
                    else ovf = 1u;
                }
                cur += (unsigned)__popcll(mask);
            }
        }
    }
    // zero-fill padding (later phases skip k < K0; 0 < K0)
    for (unsigned j = cur + lane; j < REG; j += 64) {
        unsigned gi = base + j;
        if (gi < cap_words) cand[gi] = 0u;
    }
    if (base + REG > cap_words) ovf = 1u;     // region didn't fit
    ps = wred(ps);
    kmax = wredmax(kmax);
    unsigned anyovf = (__ballot(ovf != 0u) != 0ull) ? 0x80000000u : 0u;
    if (lane == 0) {
        ws[OFF_CNT + waveid] = (cur & 0x7FFFFFFFu) | anyovf;
        ((float*)ws)[OFF_POSP + waveid] = ps;
        ws[OFF_MAXK + waveid] = kmax;
    }
    // merge LDS hist into partial (blockIdx % NPART); only nonzero bins
    __syncthreads();
    unsigned* part = ws + OFF_H1P + (blockIdx.x & (NPART - 1)) * 1024;
    for (int i = tid; i < 1024; i += NT)
        if (h[i]) atomicAdd(&part[i], h[i]);
}

// ---- correct single-block fallback: coarse 3-level select from x,y ----
// Never taken for the bench input. Tail block, NT threads. ha = 4096-word
// LDS, reused across levels (h3c/h3f overlay ha[0..2047] after b2 fixed).
__device__ void slow_select(const float* __restrict__ x, const float* __restrict__ y,
                            unsigned* __restrict__ ws, int n, unsigned Kneg, int pos,
                            float psum, float* __restrict__ out, unsigned* ha) {
    const int t = threadIdx.x;
    __shared__ unsigned bc[2];
    // L1 coarse
    for (int i = t; i < 1024; i += NT) ha[i] = 0u;
    __syncthreads();
    for (int i = t; i < n; i += NT)
        if (y[i] == 0.0f) atomicAdd(&ha[hl1(f2key(x[i]))], 1u);
    __syncthreads();
    if (t == 0) {
        unsigned cum = 0, b = 0, r = 1;
        for (int bin = 1023; bin >= 0; --bin) {
            unsigned v = ha[bin];
            if (cum + v >= Kneg) { b = (unsigned)bin; r = Kneg - cum; break; }
            cum += v;
        }
        bc[0] = b; bc[1] = r;
    }
    __syncthreads();
    const unsigned b1 = bc[0], r1 = bc[1];
    __syncthreads();
    // L2
    for (int i = t; i < 4096; i += NT) ha[i] = 0u;
    __syncthreads();
    float ss = 0.0f;
    for (int i = t; i < n; i += NT)
        if (y[i] == 0.0f) {
            unsigned k = f2key(x[i]);
            unsigned b = hl1(k);
            if (b > b1) ss += softplusf(key2f(k));
            else if (b == b1) atomicAdd(&ha[hl2(k)], 1u);
        }
    __syncthreads();
    if (t == 0) {
        unsigned cum = 0, b = 0, r = 1;
        for (int bin = 4095; bin >= 0; --bin) {
            unsigned v = ha[bin];
            if (cum + v >= r1) { b = (unsigned)bin; r = r1 - cum; break; }
            cum += v;
        }
        bc[0] = b; bc[1] = r;
    }
    __syncthreads();
    const unsigned b2 = bc[0], r2 = bc[1];
    __syncthreads();
    // L3 (overlay ha[0..2047]; hist data no longer needed)
    unsigned* h3c = ha;
    float* h3f = (float*)(ha + 1024);
    for (int i = t; i < 2048; i += NT) ha[i] = 0u;
    __syncthreads();
    float s2 = 0.0f;
    for (int i = t; i < n; i += NT)
        if (y[i] == 0.0f) {
            unsigned k = f2key(x[i]);
            if (hl1(k) == b1) {
                unsigned l2 = hl2(k);
                if (l2 > b2) s2 += softplusf(key2f(k));
                else if (l2 == b2) {
                    atomicAdd(&h3c[hl3(k)], 1u);
                    atomicAdd(&h3f[hl3(k)], softplusf(key2f(k)));
                }
            }
        }
    __syncthreads();
    ss = bred(ss);
    s2 = bred(s2);
    if (t == 0) {
        unsigned cum = 0, c3 = 0, r3 = 1;
        for (int bin = 1023; bin >= 0; --bin) {
            unsigned v = h3c[bin];
            if (cum + v >= r2) { c3 = (unsigned)bin; r3 = r2 - cum; break; }
            cum += v;
        }
        float sf = 0.0f;
        for (int j = (int)c3 + 1; j < 1024; ++j) sf += h3f[j];
        unsigned H = (b1 << 22) | (b2 << 10) | c3;
        out[0] = (psum + ss + s2 + sf + (float)r3 * softplusf(key2f(H)))
                 / (float)(4 * pos);
    }
}

// ---- k_BC: slot-reduce + scan1 + cand stream; TAIL BLOCK runs phase C ----
__global__ __launch_bounds__(NT)
void k_BC(const float* __restrict__ x, const float* __restrict__ y,
          unsigned* __restrict__ ws, const int* __restrict__ pos_num,
          int n, float* __restrict__ out) {
    __shared__ unsigned smbuf[4096];   // C: hist2; slow: ha
    __shared__ unsigned h3c[16];
    __shared__ float    h3f[16];
    __shared__ unsigned rk_sh;
    const int tid = threadIdx.x;
    const int lane = tid & 63;
    const int posn = pos_num[0];
    const unsigned Kneg = (unsigned)(posn * 3);

    // ---- slot-reduce (redundant per block; tail block keeps results) ----
    unsigned tot = 0u, mk = 0u, ov = 0u;
    float psum = 0.0f;
    for (unsigned i = tid; i < NWAVES; i += NT) {
        unsigned cc = ws[OFF_CNT + i];
        tot += cc & 0x7FFFFFFFu;
        ov |= cc >> 31;
        mk = max(mk, ws[OFF_MAXK + i]);
        psum += ((float*)ws)[OFF_POSP + i];
    }
    blockreduce4(tot, mk, ov, psum);
    const bool hard = (tot < Kneg) || (mk >= FINE_LIMIT) || (ov != 0u);

    unsigned b1 = 0u, r1 = 1u;
    if (!hard) {
        scan_desc<NT>(ws + OFF_H1P, NPART, 1024, 1024, Kneg, &b1, &r1);
        const unsigned wv = blockIdx.x * (NT / 64) + (unsigned)(tid >> 6);
        unsigned cur2 = 0u;
        float ssv = 0.0f;
        const uint4* c4 = (const uint4*)(ws + OFF_CAND);
        for (unsigned i = blockIdx.x * NT + tid; i < (unsigned)(CANDW / 4); i += BBLK * NT) {
            uint4 v = c4[i];
            unsigned ks[4] = {v.x, v.y, v.z, v.w};
#pragma unroll
            for (int cc = 0; cc < 4; ++cc) {
                unsigned k = ks[cc];
                bool ge = (k >= K0);
                unsigned b = ge ? fl1(k - K0) : 0u;
                if (ge && b > b1) ssv += softplusf(key2f(k));
                bool hit = ge && (b == b1);
                unsigned long long m = __ballot(hit);
                if (m) {
                    if (hit) {
                        unsigned slot = cur2 + (unsigned)__popcll(m & ((1ull << lane) - 1ull));
                        if (slot < (unsigned)REG2) ws[OFF_CAND2 + wv * REG2 + slot] = k;
                    }
                    cur2 += (unsigned)__popcll(m);
                }
            }
        }
        if (lane == 0) {
            ws[OFF_CNT2 + wv] = cur2 < (unsigned)REG2 ? cur2 : (unsigned)REG2;
            if (cur2 > (unsigned)REG2) ws[OFF_FLG] = 1u;   // benign same-value race
        }
        ssv = bred(ssv);
        if (tid == 0) ((float*)ws)[OFF_SS + blockIdx.x] = ssv;
    }

    // ---- tail-block arrival: one RMW, NO waiting; rank BBLK-1 continues ----
    __syncthreads();
    __threadfence();
    if (tid == 0)
        rk_sh = __hip_atomic_fetch_add(&ws[OFF_DONE], 1u, __ATOMIC_ACQ_REL,
                                       __HIP_MEMORY_SCOPE_AGENT);
    __syncthreads();
    if (rk_sh != (unsigned)(BBLK - 1)) return;
    __threadfence();

    // ======== Phase C (tail block only) ========
    const bool slow = hard || (ws[OFF_FLG] != 0u);
    if (slow) {
        slow_select(x, y, ws, n, Kneg, posn, psum, out, smbuf);
        return;
    }
    // hist2 over b1-keys from per-wave global regions
    for (int i = tid; i < 4096; i += NT) smbuf[i] = 0u;
    __syncthreads();
    for (int rr = 0; rr < SELWAVES / NT; ++rr) {
        const unsigned region = (unsigned)tid + (unsigned)rr * NT;
        const unsigned cnt = ws[OFF_CNT2 + region];      // clamped <= REG2
        const unsigned rbase = OFF_CAND2 + region * REG2;
        for (unsigned j = 0; j < cnt; ++j)
            atomicAdd(&smbuf[fl2(ws[rbase + j] - K0)], 1u);
    }
    __syncthreads();
    unsigned b2, r2;
    scan_desc<NT>(smbuf, 1, 0, 4096, r1, &b2, &r2);
    if (tid < 16) { h3c[tid] = 0u; h3f[tid] = 0.0f; }
    __syncthreads();
    float s2 = 0.0f;
    for (int rr = 0; rr < SELWAVES / NT; ++rr) {
        const unsigned region = (unsigned)tid + (unsigned)rr * NT;
        const unsigned cnt = ws[OFF_CNT2 + region];
        const unsigned rbase = OFF_CAND2 + region * REG2;
        for (unsigned j = 0; j < cnt; ++j) {
            unsigned k = ws[rbase + j];
            unsigned l2 = fl2(k - K0);
            if (l2 > b2) s2 += softplusf(key2f(k));
            else if (l2 == b2) {
                atomicAdd(&h3c[fl3(k - K0)], 1u);
                atomicAdd(&h3f[fl3(k - K0)], softplusf(key2f(k)));
            }
        }
    }
    __syncthreads();
    s2 = bred(s2);
    float ssT = bred(((float*)ws)[OFF_SS + tid]);    // NT == BBLK slots
    if (tid == 0) {
        unsigned cum = 0, c3 = 0, r3 = 1;
        for (int bin = 15; bin >= 0; --bin) {
            unsigned v = h3c[bin];
            if (cum + v >= r2) { c3 = (unsigned)bin; r3 = r2 - cum; break; }
            cum += v;
        }
        float sf = 0.0f;
        for (int j = (int)c3 + 1; j < 16; ++j) sf += h3f[j];
        unsigned H = K0 + ((b1 << 16) | (b2 << 4) | c3);
        out[0] = (psum + ssT + s2 + sf + (float)r3 * softplusf(key2f(H)))
                 / (float)(4 * posn);
    }
}

extern "C" void kernel_launch(void* const* d_in, const int* in_sizes, int n_in,
                              void* d_out, int out_size, void* d_ws, size_t ws_size,
                              hipStream_t stream) {
    const float* x = (const float*)d_in[0];
    const float* y = (const float*)d_in[1];
    const int* pos_num = (const int*)d_in[2];
    float* out = (float*)d_out;
    const int n = in_sizes[0];

    unsigned* ws = (unsigned*)d_ws;
    unsigned cap_words = 0u;
    if (ws_size / 4 > (size_t)OFF_CAND)
        cap_words = (unsigned)(ws_size / 4 - OFF_CAND);
    if (cap_words > (unsigned)CANDW) cap_words = (unsigned)CANDW;

    hipMemsetAsync(d_ws, 0, ZERO_BYTES, stream);   // FLG/DONE + L1 partials
    k_main<<<GRID, NT, 0, stream>>>(x, y, ws, cap_words, n);
    k_BC<<<BBLK, NT, 0, stream>>>(x, y, ws, pos_num, n, out);
}